// Round 7
// baseline (405.052 us; speedup 1.0000x reference)
//
#include <hip/hip_runtime.h>
#include <math.h>

// Problem constants
#define Bn 2
#define Sn 512
#define Hn 128
#define NHn 4
#define Dn 32
#define BAGn 5
#define NMETAn 16
#define ROWS 1024
#define NBn 2
#define Tt 257

#define NEGF (-4294967295.0f)
#define INV_SQRT_D 0.17677669529663687f
#define SQRT_H 11.313708498984761f
#define EPS_EMB 1e-5f
#define EPSF 1e-8f

// workspace float offsets
#define OFF_QN    0
#define OFF_Q     131072
#define OFF_K     262144
#define OFF_V     393216
#define OFF_O     524288
#define OFF_FUSWT 655360          // 256*128
#define OFF_QWT   688128          // 2*16384
#define OFF_KWT   720896
#define OFF_VWT   753664
#define OFF_W1WT  786432
#define OFF_W2WT  819200

static __device__ __forceinline__ float red64(float v) {
#pragma unroll
    for (int m = 1; m < 64; m <<= 1) v += __shfl_xor(v, m, 64);
    return v;
}
static __device__ __forceinline__ float red64max(float v) {
#pragma unroll
    for (int m = 1; m < 64; m <<= 1) v = fmaxf(v, __shfl_xor(v, m, 64));
    return v;
}

// ---------------------------------------------------------------------------
// Transpose weight matrices into ws (once per call).
// ---------------------------------------------------------------------------
__global__ __launch_bounds__(256) void transpose_all(
    const float* __restrict__ fusW, const float* __restrict__ QW,
    const float* __restrict__ KW, const float* __restrict__ VW,
    const float* __restrict__ w1W, const float* __restrict__ w2W,
    float* __restrict__ ws)
{
    int bid = blockIdx.x;
    const float* src; float* dst; int C, tile;
    if (bid < 32) { src = fusW; dst = ws + OFF_FUSWT; C = 256; tile = bid; }
    else {
        int m = (bid - 32) >> 4; tile = (bid - 32) & 15; C = 128;
        switch (m) {
            case 0: src = QW;          dst = ws + OFF_QWT;          break;
            case 1: src = QW + 16384;  dst = ws + OFF_QWT + 16384;  break;
            case 2: src = KW;          dst = ws + OFF_KWT;          break;
            case 3: src = KW + 16384;  dst = ws + OFF_KWT + 16384;  break;
            case 4: src = VW;          dst = ws + OFF_VWT;          break;
            case 5: src = VW + 16384;  dst = ws + OFF_VWT + 16384;  break;
            case 6: src = w1W;         dst = ws + OFF_W1WT;         break;
            case 7: src = w1W + 16384; dst = ws + OFF_W1WT + 16384; break;
            case 8: src = w2W;         dst = ws + OFF_W2WT;         break;
            default:src = w2W + 16384; dst = ws + OFF_W2WT + 16384; break;
        }
    }
    int ctiles = C >> 5;
    int rt = tile / ctiles, ct = tile % ctiles;
    int r0 = rt * 32, c0 = ct * 32;
    __shared__ float ts[32][33];
    int c = threadIdx.x & 31, r = threadIdx.x >> 5;
#pragma unroll
    for (int rr = r; rr < 32; rr += 8)
        ts[rr][c] = src[(r0 + rr) * C + c0 + c];
    __syncthreads();
    int rr2 = threadIdx.x & 31, cb = threadIdx.x >> 5;
#pragma unroll
    for (int cc = cb; cc < 32; cc += 8)
        dst[(c0 + cc) * 128 + r0 + rr2] = ts[rr2][cc];
}

// ---------------------------------------------------------------------------
// Fused embed -> emb LN -> keep -> attn LN(0) -> QKV(0). 2 rows/block.
// ---------------------------------------------------------------------------
__global__ __launch_bounds__(256) void embed_qkv_kernel(
    const int* __restrict__ ids, const float* __restrict__ meta,
    const int* __restrict__ cats,
    const float* __restrict__ item_w, const float* __restrict__ cat_w,
    const float* __restrict__ numW, const float* __restrict__ numb,
    const float* __restrict__ fusWT, const float* __restrict__ fusb,
    const float* __restrict__ elng, const float* __restrict__ elnb,
    const float* __restrict__ alng, const float* __restrict__ alnb,
    const float* __restrict__ QWT, const float* __restrict__ Qb,
    const float* __restrict__ KWT, const float* __restrict__ Kb,
    const float* __restrict__ VWT, const float* __restrict__ Vb,
    const float* __restrict__ posK, const float* __restrict__ posV,
    float* __restrict__ Qn, float* __restrict__ Q,
    float* __restrict__ K, float* __restrict__ V)
{
    int r0 = blockIdx.x * 2, t = threadIdx.x;
    __shared__ float combs[512], xs[256], qs[256], parts[256], pk[256], pv[256];
    __shared__ float wsum[8];
    __shared__ int idl[2];
    if (t < 2) idl[t] = ids[r0 + t];
    __syncthreads();
    { int r = t >> 7, c = t & 127; combs[r * 256 + c] = item_w[idl[r] * Hn + c] * SQRT_H; }
    if (t < 128) {
        int r = t >> 6, c = t & 63;
        float acc = numb[c];
#pragma unroll
        for (int m2 = 0; m2 < NMETAn; ++m2)
            acc += meta[(r0 + r) * NMETAn + m2] * numW[c * NMETAn + m2];
        combs[r * 256 + 128 + c] = acc;
    } else {
        int u = t - 128, r = u >> 6, c = u & 63;
        float ca = 0.f; int cnt = 0;
#pragma unroll
        for (int k2 = 0; k2 < BAGn; ++k2) {
            int cc2 = cats[(r0 + r) * BAGn + k2];
            if (cc2 != 0) { ca += cat_w[cc2 * 64 + c]; cnt++; }
        }
        combs[r * 256 + 192 + c] = ca / (float)(cnt > 0 ? cnt : 1);
    }
    __syncthreads();
    int h = t & 127, kh = t >> 7;
    // fusion GEMM, 2 accs per output (4 chains of 64)
    {
        float a0a = 0.f, a0b = 0.f, a1a = 0.f, a1b = 0.f;
        int kbase = kh * 128;
        for (int k = kbase; k < kbase + 128; k += 2) {
            float wa = fusWT[k * 128 + h], wb = fusWT[(k + 1) * 128 + h];
            a0a += combs[k] * wa;       a0b += combs[k + 1] * wb;
            a1a += combs[256 + k] * wa; a1b += combs[256 + k + 1] * wb;
        }
        float a0 = a0a + a0b, a1 = a1a + a1b;
        if (kh) { parts[h] = a0; parts[128 + h] = a1; }
        __syncthreads();
        if (!kh) {
            xs[h] = a0 + parts[h] + fusb[h];
            xs[128 + h] = a1 + parts[128 + h] + fusb[h];
        }
    }
    __syncthreads();
    // emb LN + keep
    int w_ = t >> 6, row = w_ >> 1, l = t & 63, ch = ((w_ & 1) << 6) + l;
    float x = xs[row * 128 + ch];
    float s1 = red64(x);
    if (l == 0) wsum[w_] = s1;
    __syncthreads();
    float mean = (wsum[row * 2] + wsum[row * 2 + 1]) * (1.f / 128.f);
    float dlt = x - mean;
    float s2 = red64(dlt * dlt);
    if (l == 0) wsum[4 + w_] = s2;
    __syncthreads();
    float rstd = rsqrtf((wsum[4 + row * 2] + wsum[4 + row * 2 + 1]) * (1.f / 128.f) + EPS_EMB);
    float xv = dlt * rstd * elng[ch] + elnb[ch];
    xv = (idl[row] == 0) ? 0.f : xv;
    __syncthreads();
    xs[row * 128 + ch] = xv;
    __syncthreads();
    // attn LN (nb=0)
    s1 = red64(xv);
    if (l == 0) wsum[w_] = s1;
    __syncthreads();
    mean = (wsum[row * 2] + wsum[row * 2 + 1]) * (1.f / 128.f);
    dlt = xv - mean;
    s2 = red64(dlt * dlt);
    if (l == 0) wsum[4 + w_] = s2;
    __syncthreads();
    rstd = rsqrtf((wsum[4 + row * 2] + wsum[4 + row * 2 + 1]) * (1.f / 128.f) + EPSF);
    float qn = dlt * rstd * alng[ch] + alnb[ch];
    qs[row * 128 + ch] = qn;
    Qn[(r0 + row) * 128 + ch] = qn;
    __syncthreads();
    // QKV GEMMs (nb=0)
    float aq0 = 0, aq1 = 0, ak0 = 0, ak1 = 0, av0 = 0, av1 = 0;
    for (int k = kh * 64; k < kh * 64 + 64; ++k) {
        float wq = QWT[k * 128 + h], wk = KWT[k * 128 + h], wv = VWT[k * 128 + h];
        float q0 = qs[k], q1 = qs[128 + k], x0 = xs[k], x1 = xs[128 + k];
        aq0 += q0 * wq; aq1 += q1 * wq;
        ak0 += x0 * wk; ak1 += x1 * wk;
        av0 += x0 * wv; av1 += x1 * wv;
    }
    if (kh) {
        parts[h] = aq0; parts[128 + h] = aq1;
        pk[h] = ak0; pk[128 + h] = ak1;
        pv[h] = av0; pv[128 + h] = av1;
    }
    __syncthreads();
    if (!kh) {
        int s0 = r0 & (Sn - 1), s1_ = (r0 + 1) & (Sn - 1);
        Q[r0 * 128 + h]       = aq0 + parts[h]       + Qb[h];
        Q[(r0 + 1) * 128 + h] = aq1 + parts[128 + h] + Qb[h];
        K[r0 * 128 + h]       = ak0 + pk[h]          + Kb[h] + posK[s0 * 128 + h];
        K[(r0 + 1) * 128 + h] = ak1 + pk[128 + h]    + Kb[h] + posK[s1_ * 128 + h];
        V[r0 * 128 + h]       = av0 + pv[h]          + Vb[h] + posV[s0 * 128 + h];
        V[(r0 + 1) * 128 + h] = av1 + pv[128 + h]    + Vb[h] + posV[s1_ * 128 + h];
    }
}

// ---------------------------------------------------------------------------
// Attention: block = (b,h, contiguous 4-query tile). Fused per-block QT.
// ILP: 4 accumulators in score dot and PV loop.
// ---------------------------------------------------------------------------
__global__ __launch_bounds__(256) void attn_kernel(
    const int* __restrict__ ids, const int* __restrict__ tmat,
    const float* __restrict__ Q, const float* __restrict__ K,
    const float* __restrict__ V,
    const float* __restrict__ tKw, const float* __restrict__ tVw,
    float* __restrict__ O)
{
    int blk = blockIdx.x, t = threadIdx.x;
    int bh = blk >> 7, itile = blk & 127, i0 = itile * 4;
    int b = bh >> 2, h = bh & 3;

    __shared__ float Kt[64 * 33];
    __shared__ float S[4 * 512];
    __shared__ float QTl[4 * 260];
    __shared__ float ql[4 * 33];
    __shared__ float parts[256];
    __shared__ float invl[4];
    __shared__ int tlf[4];

    if (t < 4) tlf[t] = (ids[b * Sn + i0 + t] == 0) ? 1 : 0;
    if (t < 128) {
        int q_ = t >> 5, d = t & 31;
        ql[q_ * 33 + d] = Q[(b * Sn + i0 + q_) * Hn + h * 32 + d];
    }
    __syncthreads();

    // fused QT: thread tt computes Q_i . timeK[tt] for the 4 queries
    for (int tt = t; tt < Tt; tt += 256) {
        const float4* tk4 = (const float4*)(tKw + tt * Hn + h * 32);
        float a0 = 0.f, a1 = 0.f, a2 = 0.f, a3 = 0.f;
#pragma unroll
        for (int dv = 0; dv < 8; ++dv) {
            float4 w4 = tk4[dv];
            int d = dv * 4;
            a0 += ql[d] * w4.x + ql[d + 1] * w4.y + ql[d + 2] * w4.z + ql[d + 3] * w4.w;
            a1 += ql[33 + d] * w4.x + ql[34 + d] * w4.y + ql[35 + d] * w4.z + ql[36 + d] * w4.w;
            a2 += ql[66 + d] * w4.x + ql[67 + d] * w4.y + ql[68 + d] * w4.z + ql[69 + d] * w4.w;
            a3 += ql[99 + d] * w4.x + ql[100 + d] * w4.y + ql[101 + d] * w4.z + ql[102 + d] * w4.w;
        }
        QTl[tt] = a0; QTl[260 + tt] = a1; QTl[520 + tt] = a2; QTl[780 + tt] = a3;
    }

    int tl_any = tlf[0] | tlf[1] | tlf[2] | tlf[3];
    int ntiles = tl_any ? 8 : ((i0 + 3) >> 6) + 1;
    int n = ntiles * 64;

    int iq = t >> 6, jj = t & 63;
    int i_g = i0 + iq;
    int my_tl = tlf[iq];
    const int* trow = tmat + (b * Sn + i_g) * Sn;

    // ---- scores ----
    for (int jt = 0; jt < ntiles; ++jt) {
        int j0 = jt * 64;
        __syncthreads();
        for (int f = t; f < 64 * 8; f += 256) {
            int jl = f >> 3, dv = f & 7;
            float4 w4 = *(const float4*)(K + (b * Sn + j0 + jl) * Hn + h * 32 + dv * 4);
            float* kd = &Kt[jl * 33 + dv * 4];
            kd[0] = w4.x; kd[1] = w4.y; kd[2] = w4.z; kd[3] = w4.w;
        }
        __syncthreads();
        int j = j0 + jj;
        float sv = NEGF;
        if (!my_tl && j <= i_g) {
            float a0 = 0.f, a1 = 0.f, a2 = 0.f, a3 = 0.f;
#pragma unroll
            for (int d8 = 0; d8 < 8; ++d8) {
                int d = d8 * 4;
                a0 += ql[iq * 33 + d]     * Kt[jj * 33 + d];
                a1 += ql[iq * 33 + d + 1] * Kt[jj * 33 + d + 1];
                a2 += ql[iq * 33 + d + 2] * Kt[jj * 33 + d + 2];
                a3 += ql[iq * 33 + d + 3] * Kt[jj * 33 + d + 3];
            }
            sv = ((a0 + a1) + (a2 + a3) + QTl[iq * 260 + trow[j]]) * INV_SQRT_D;
        }
        S[iq * 512 + j] = sv;
    }

    // ---- per-wave softmax (wave iq wrote all of row iq) ----
    float lm = -INFINITY;
    for (int j = jj; j < n; j += 64) lm = fmaxf(lm, S[iq * 512 + j]);
    lm = red64max(lm);
    float ls = 0.f;
    for (int j = jj; j < n; j += 64) {
        float e = expf(S[iq * 512 + j] - lm);
        S[iq * 512 + j] = e;
        ls += e;
    }
    ls = red64(ls);
    if (jj == 0) invl[iq] = 1.f / ls;

    // ---- PV (4 accumulators, p-guarded gathers) ----
    int jq = (t >> 5) & 1, d = t & 31;
    float c0 = 0.f, c1 = 0.f, c2 = 0.f, c3 = 0.f;
    for (int jt = 0; jt < ntiles; ++jt) {
        int j0 = jt * 64;
        __syncthreads();
        for (int f = t; f < 64 * 8; f += 256) {
            int jl = f >> 3, dv = f & 7;
            float4 w4 = *(const float4*)(V + (b * Sn + j0 + jl) * Hn + h * 32 + dv * 4);
            float* kd = &Kt[jl * 33 + dv * 4];
            kd[0] = w4.x; kd[1] = w4.y; kd[2] = w4.z; kd[3] = w4.w;
        }
        __syncthreads();
        if (my_tl || j0 <= i_g) {
            int base = jq * 32;
#pragma unroll
            for (int u = 0; u < 8; ++u) {
                int jl = base + u * 4;
                float p0 = S[iq * 512 + j0 + jl];
                float p1 = S[iq * 512 + j0 + jl + 1];
                float p2 = S[iq * 512 + j0 + jl + 2];
                float p3 = S[iq * 512 + j0 + jl + 3];
                if (p0 != 0.f) c0 += p0 * (Kt[jl * 33 + d]       + tVw[trow[j0 + jl]     * Hn + h * 32 + d]);
                if (p1 != 0.f) c1 += p1 * (Kt[(jl + 1) * 33 + d] + tVw[trow[j0 + jl + 1] * Hn + h * 32 + d]);
                if (p2 != 0.f) c2 += p2 * (Kt[(jl + 2) * 33 + d] + tVw[trow[j0 + jl + 2] * Hn + h * 32 + d]);
                if (p3 != 0.f) c3 += p3 * (Kt[(jl + 3) * 33 + d] + tVw[trow[j0 + jl + 3] * Hn + h * 32 + d]);
            }
        }
    }
    parts[t] = (c0 + c1) + (c2 + c3);
    __syncthreads();
    if (t < 128) {
        int iq2 = t >> 5, d2 = t & 31;
        float a = parts[iq2 * 64 + d2] + parts[iq2 * 64 + 32 + d2];
        O[(b * Sn + i0 + iq2) * Hn + h * 32 + d2] = a * invl[iq2];
    }
}

// ---------------------------------------------------------------------------
// Fused FFN(nb) -> [attn LN(nb+1)+QKV(nb+1)] or [final LN -> out]. 2 rows/blk.
// ---------------------------------------------------------------------------
__global__ __launch_bounds__(256) void ffn_qkv_kernel(
    const int* __restrict__ ids,
    float* __restrict__ Qn, const float* __restrict__ O,
    const float* __restrict__ flng, const float* __restrict__ flnb,
    const float* __restrict__ w1WT, const float* __restrict__ w1b,
    const float* __restrict__ w2WT, const float* __restrict__ w2b,
    const float* __restrict__ alng, const float* __restrict__ alnb,
    const float* __restrict__ QWT, const float* __restrict__ Qb,
    const float* __restrict__ KWT, const float* __restrict__ Kb,
    const float* __restrict__ VWT, const float* __restrict__ Vb,
    const float* __restrict__ posK, const float* __restrict__ posV,
    float* __restrict__ Q, float* __restrict__ K, float* __restrict__ V,
    const float* __restrict__ llng, const float* __restrict__ llnb,
    float* __restrict__ out, int nb, int last)
{
    int r0 = blockIdx.x * 2, t = threadIdx.x;
    __shared__ float ys[256], h1s[256], parts[256], pk[256], pv[256];
    __shared__ float wsum[8];
    ys[t] = Qn[r0 * 128 + t] + O[r0 * 128 + t];
    __syncthreads();
    int w_ = t >> 6, row = w_ >> 1, l = t & 63, ch = ((w_ & 1) << 6) + l;
    // fwd LN
    float x = ys[row * 128 + ch];
    float s1 = red64(x);
    if (l == 0) wsum[w_] = s1;
    __syncthreads();
    float mean = (wsum[row * 2] + wsum[row * 2 + 1]) * (1.f / 128.f);
    float dlt = x - mean;
    float s2 = red64(dlt * dlt);
    if (l == 0) wsum[4 + w_] = s2;
    __syncthreads();
    float rstd = rsqrtf((wsum[4 + row * 2] + wsum[4 + row * 2 + 1]) * (1.f / 128.f) + EPSF);
    float yv = dlt * rstd * flng[nb * 128 + ch] + flnb[nb * 128 + ch];
    __syncthreads();
    ys[row * 128 + ch] = yv;
    __syncthreads();

    int h = t & 127, kh = t >> 7;
    const float* w1 = w1WT + nb * 16384;
    // GEMM1, 2 accs per output
    {
        float a0a = 0.f, a0b = 0.f, a1a = 0.f, a1b = 0.f;
        int kbase = kh * 64;
        for (int k = kbase; k < kbase + 64; k += 2) {
            float wa = w1[k * 128 + h], wb = w1[(k + 1) * 128 + h];
            a0a += ys[k] * wa;       a0b += ys[k + 1] * wb;
            a1a += ys[128 + k] * wa; a1b += ys[128 + k + 1] * wb;
        }
        float a10 = a0a + a0b, a11 = a1a + a1b;
        if (kh) { parts[h] = a10; parts[128 + h] = a11; }
        __syncthreads();
        if (!kh) {
            float v0 = a10 + parts[h] + w1b[nb * 128 + h];
            float v1 = a11 + parts[128 + h] + w1b[nb * 128 + h];
            h1s[h] = 0.5f * v0 * (1.f + erff(v0 * 0.70710678118654752f));
            h1s[128 + h] = 0.5f * v1 * (1.f + erff(v1 * 0.70710678118654752f));
        }
    }
    __syncthreads();
    const float* w2 = w2WT + nb * 16384;
    // GEMM2, 2 accs per output
    {
        float a0a = 0.f, a0b = 0.f, a1a = 0.f, a1b = 0.f;
        int kbase = kh * 64;
        for (int k = kbase; k < kbase + 64; k += 2) {
            float wa = w2[k * 128 + h], wb = w2[(k + 1) * 128 + h];
            a0a += h1s[k] * wa;       a0b += h1s[k + 1] * wb;
            a1a += h1s[128 + k] * wa; a1b += h1s[128 + k + 1] * wb;
        }
        float a20 = a0a + a0b, a21 = a1a + a1b;
        __syncthreads();
        if (kh) { parts[h] = a20; parts[128 + h] = a21; }
        __syncthreads();
        if (!kh) {
            float z0 = a20 + parts[h] + w2b[nb * 128 + h] + ys[h];
            float z1 = a21 + parts[128 + h] + w2b[nb * 128 + h] + ys[128 + h];
            z0 = (ids[r0] == 0) ? 0.f : z0;
            z1 = (ids[r0 + 1] == 0) ? 0.f : z1;
            h1s[h] = z0; h1s[128 + h] = z1;
        }
    }
    __syncthreads();

    if (last) {
        // final LN -> out
        x = h1s[row * 128 + ch];
        s1 = red64(x);
        if (l == 0) wsum[w_] = s1;
        __syncthreads();
        mean = (wsum[row * 2] + wsum[row * 2 + 1]) * (1.f / 128.f);
        dlt = x - mean;
        s2 = red64(dlt * dlt);
        if (l == 0) wsum[4 + w_] = s2;
        __syncthreads();
        rstd = rsqrtf((wsum[4 + row * 2] + wsum[4 + row * 2 + 1]) * (1.f / 128.f) + EPSF);
        out[(r0 + row) * 128 + ch] = dlt * rstd * llng[ch] + llnb[ch];
        return;
    }

    // attn LN (nb+1) + QKV(nb+1)
    int nq = nb + 1;
    x = h1s[row * 128 + ch];
    s1 = red64(x);
    if (l == 0) wsum[w_] = s1;
    __syncthreads();
    mean = (wsum[row * 2] + wsum[row * 2 + 1]) * (1.f / 128.f);
    dlt = x - mean;
    s2 = red64(dlt * dlt);
    if (l == 0) wsum[4 + w_] = s2;
    __syncthreads();
    rstd = rsqrtf((wsum[4 + row * 2] + wsum[4 + row * 2 + 1]) * (1.f / 128.f) + EPSF);
    float qn = dlt * rstd * alng[nq * 128 + ch] + alnb[nq * 128 + ch];
    __syncthreads();
    ys[row * 128 + ch] = qn;           // ys := qs
    Qn[(r0 + row) * 128 + ch] = qn;
    __syncthreads();

    float aq0 = 0, aq1 = 0, ak0 = 0, ak1 = 0, av0 = 0, av1 = 0;
    const float* qwt = QWT + nq * 16384;
    const float* kwt = KWT + nq * 16384;
    const float* vwt = VWT + nq * 16384;
    for (int k = kh * 64; k < kh * 64 + 64; ++k) {
        float wq = qwt[k * 128 + h], wk = kwt[k * 128 + h], wv = vwt[k * 128 + h];
        float q0 = ys[k], q1 = ys[128 + k], x0 = h1s[k], x1 = h1s[128 + k];
        aq0 += q0 * wq; aq1 += q1 * wq;
        ak0 += x0 * wk; ak1 += x1 * wk;
        av0 += x0 * wv; av1 += x1 * wv;
    }
    if (kh) {
        parts[h] = aq0; parts[128 + h] = aq1;
        pk[h] = ak0; pk[128 + h] = ak1;
        pv[h] = av0; pv[128 + h] = av1;
    }
    __syncthreads();
    if (!kh) {
        int s0 = r0 & (Sn - 1), s1_ = (r0 + 1) & (Sn - 1);
        Q[r0 * 128 + h]       = aq0 + parts[h]       + Qb[nq * 128 + h];
        Q[(r0 + 1) * 128 + h] = aq1 + parts[128 + h] + Qb[nq * 128 + h];
        K[r0 * 128 + h]       = ak0 + pk[h]          + Kb[nq * 128 + h] + posK[s0 * 128 + h];
        K[(r0 + 1) * 128 + h] = ak1 + pk[128 + h]    + Kb[nq * 128 + h] + posK[s1_ * 128 + h];
        V[r0 * 128 + h]       = av0 + pv[h]          + Vb[nq * 128 + h] + posV[s0 * 128 + h];
        V[(r0 + 1) * 128 + h] = av1 + pv[128 + h]    + Vb[nq * 128 + h] + posV[s1_ * 128 + h];
    }
}

// ---------------------------------------------------------------------------
extern "C" void kernel_launch(void* const* d_in, const int* in_sizes, int n_in,
                              void* d_out, int out_size, void* d_ws, size_t ws_size,
                              hipStream_t stream) {
    const int*   ids   = (const int*)  d_in[0];
    const float* meta  = (const float*)d_in[1];
    const int*   cats  = (const int*)  d_in[2];
    const int*   tmat  = (const int*)  d_in[3];
    const float* itemw = (const float*)d_in[4];
    const float* catw  = (const float*)d_in[5];
    const float* numW  = (const float*)d_in[6];
    const float* numb  = (const float*)d_in[7];
    const float* fusW  = (const float*)d_in[8];
    const float* fusb  = (const float*)d_in[9];
    const float* elng  = (const float*)d_in[10];
    const float* elnb  = (const float*)d_in[11];
    const float* posK  = (const float*)d_in[12];
    const float* posV  = (const float*)d_in[13];
    const float* tKw   = (const float*)d_in[14];
    const float* tVw   = (const float*)d_in[15];
    const float* alng  = (const float*)d_in[16];
    const float* alnb  = (const float*)d_in[17];
    const float* QW    = (const float*)d_in[18];
    const float* Qb    = (const float*)d_in[19];
    const float* KW    = (const float*)d_in[20];
    const float* Kb    = (const float*)d_in[21];
    const float* VW    = (const float*)d_in[22];
    const float* Vb    = (const float*)d_in[23];
    const float* flng  = (const float*)d_in[24];
    const float* flnb  = (const float*)d_in[25];
    const float* w1W   = (const float*)d_in[26];
    const float* w1b   = (const float*)d_in[27];
    const float* w2W   = (const float*)d_in[28];
    const float* w2b   = (const float*)d_in[29];
    const float* llng  = (const float*)d_in[30];
    const float* llnb  = (const float*)d_in[31];
    (void)in_sizes; (void)n_in; (void)out_size; (void)ws_size;

    float* ws = (float*)d_ws;
    float* Qn   = ws + OFF_QN;
    float* Q    = ws + OFF_Q;
    float* K    = ws + OFF_K;
    float* V    = ws + OFF_V;
    float* O    = ws + OFF_O;
    float* fusWT= ws + OFF_FUSWT;
    float* QWT  = ws + OFF_QWT;
    float* KWT  = ws + OFF_KWT;
    float* VWT  = ws + OFF_VWT;
    float* w1WT = ws + OFF_W1WT;
    float* w2WT = ws + OFF_W2WT;
    float* out  = (float*)d_out;

    transpose_all<<<192, 256, 0, stream>>>(fusW, QW, KW, VW, w1W, w2W, ws);
    embed_qkv_kernel<<<ROWS / 2, 256, 0, stream>>>(
        ids, meta, cats, itemw, catw, numW, numb, fusWT, fusb, elng, elnb,
        alng, alnb, QWT, Qb, KWT, Kb, VWT, Vb, posK, posV, Qn, Q, K, V);
    for (int nb = 0; nb < NBn; ++nb) {
        attn_kernel<<<8 * 128, 256, 0, stream>>>(ids, tmat, Q, K, V, tKw, tVw, O);
        ffn_qkv_kernel<<<ROWS / 2, 256, 0, stream>>>(
            ids, Qn, O, flng, flnb, w1WT, w1b, w2WT, w2b,
            alng, alnb, QWT, Qb, KWT, Kb, VWT, Vb, posK, posV,
            Q, K, V, llng, llnb, out, nb, (nb == NBn - 1) ? 1 : 0);
    }
}